// Round 11
// baseline (58.314 us; speedup 1.0000x reference)
//
#include <hip/hip_runtime.h>

#define N_PIX 4096
#define N_CH 256
#define KSEL 16
#define PCAP 4
#define SCAP 64

__device__ __forceinline__ unsigned f2key(float f) {
  unsigned u = __float_as_uint(f);
  return u ^ ((unsigned)((int)u >> 31) | 0x80000000u);
}
__device__ __forceinline__ float key2f(unsigned k) {
  unsigned u = (k & 0x80000000u) ? (k ^ 0x80000000u) : ~k;
  return __uint_as_float(u);
}
__device__ __forceinline__ unsigned umax2(unsigned a, unsigned b) { return a > b ? a : b; }

// feat [B, C, N] -> feat_t [B, N, C], 32x32 LDS tile transpose
__global__ void transpose_feat_kernel(const float* __restrict__ feat,
                                      float* __restrict__ feat_t) {
  __shared__ float tile[32][33];
  const int b = blockIdx.z;
  const int n0 = blockIdx.x * 32;
  const int c0 = blockIdx.y * 32;
  const int tx = threadIdx.x, ty = threadIdx.y;
  const float* src = feat + (size_t)b * N_CH * N_PIX;
  float* dst = feat_t + (size_t)b * N_PIX * N_CH;
#pragma unroll
  for (int j = 0; j < 32; j += 8)
    tile[ty + j][tx] = src[(size_t)(c0 + ty + j) * N_PIX + n0 + tx];
  __syncthreads();
#pragma unroll
  for (int j = 0; j < 32; j += 8)
    dst[(size_t)(n0 + ty + j) * N_CH + c0 + tx] = tile[tx][ty + j];
}

// 512 blocks (= 2 per CU, all waves resident) x 4 waves; each wave owns 4
// CONSECUTIVE rows, processed through a depth-2 software pipeline: row r+1's
// 16 float4 loads are issued before row r's selection, so a row-load is in
// flight at all times (FIFO vmcnt: the gather wait inside process subsumes
// the next row's aff wait). Zero __syncthreads — waves are fully independent
// and each wave's 4 rows form the full 16B span per channel (block = full
// 64B line), so per-row scalar stores write-combine in L2.
template <bool FT>
__global__ __launch_bounds__(256, 2) void topk_pipe_kernel(
    const float* __restrict__ aff, const float* __restrict__ feat,
    float* __restrict__ out) {
  __shared__ uint2 s_priv[4][64][PCAP];  // 8 KB private candidate slots
  __shared__ uint2 s_slab[4][SCAP];      // 2 KB padded candidate slab
  __shared__ uint2 s_wj[4][KSEL];        // 512 B (exp bits, idx)

  const int tid = threadIdx.x;
  const int lane = tid & 63;
  const int w = tid >> 6;
  // chunked bijective XCD swizzle (512 = 8 * 64): each XCD gets a contiguous
  // row range -> its gathers hit one batch's feat_t (4 MB, fits its L2).
  const int bid = blockIdx.x;
  const int swz = (bid & 7) * 64 + (bid >> 3);
  const int row0 = swz * 16 + w * 4;     // 4 consecutive rows for this wave
  const int b = row0 >> 12;
  const unsigned long long lt = (1ull << lane) - 1ull;

  const float* fb = FT ? (feat + (size_t)b * N_PIX * N_CH + lane * 4)
                       : (feat + (size_t)b * N_CH * N_PIX);

  // ---- process one row whose raw float4s sit in bank fv[16] ----
  auto process = [&](const float4 (&fv)[16], int row) {
    // keys + lane max
    uint4 kv[16];
    unsigned m = 0;
#pragma unroll
    for (int q = 0; q < 16; ++q) {
      const unsigned k0 = f2key(fv[q].x), k1 = f2key(fv[q].y);
      const unsigned k2 = f2key(fv[q].z), k3 = f2key(fv[q].w);
      kv[q].x = k0; kv[q].y = k1; kv[q].z = k2; kv[q].w = k3;
      m = umax2(m, umax2(umax2(k0, k1), umax2(k2, k3)));
    }

    // T1: exact 16th-largest hi-16-truncated lane max (16-step branchless radix)
    const unsigned t = m >> 16;
    unsigned p1 = 0, need1 = KSEL;
#pragma unroll
    for (int bit = 15; bit >= 0; --bit) {
      const unsigned want = (p1 << 1) | 1u;
      const unsigned cnt = (unsigned)__popcll(__ballot((t >> bit) == want));
      const bool take = cnt >= need1;
      p1 = want - (take ? 0u : 1u);
      need1 = take ? need1 : need1 - cnt;
    }
    const unsigned thrK = p1 << 16;  // >=16 elems >= thrK; all top-16 >= thrK

    // pad slab (same-wave in-order DS ops; no barrier ever needed)
    s_slab[w][lane] = make_uint2(0u, 0xFFFFFFFFu);

    // private-slot extraction (no per-element ballots)
    unsigned cl = 0;
#pragma unroll
    for (int q = 0; q < 16; ++q) {
      const unsigned kk[4] = {kv[q].x, kv[q].y, kv[q].z, kv[q].w};
#pragma unroll
      for (int c = 0; c < 4; ++c) {
        if (kk[c] >= thrK) {
          if (cl < PCAP)
            s_priv[w][lane][cl] =
                make_uint2(kk[c], (unsigned)(q * 256 + lane * 4 + c));
          ++cl;
        }
      }
    }

    unsigned total;
    if (__builtin_expect(__ballot(cl > PCAP) == 0ull, 1)) {
      // 3-ballot prefix sum of cl (0..4) -> compact positions
      const unsigned long long b0 = __ballot(cl & 1u);
      const unsigned long long b1 = __ballot(cl & 2u);
      const unsigned long long b2 = __ballot(cl & 4u);
      const unsigned start = (unsigned)__popcll(b0 & lt) +
                             2u * (unsigned)__popcll(b1 & lt) +
                             4u * (unsigned)__popcll(b2 & lt);
      total = (unsigned)__popcll(b0) + 2u * (unsigned)__popcll(b1) +
              4u * (unsigned)__popcll(b2);
      for (unsigned c = 0; c < cl; ++c) {
        const uint2 tt = s_priv[w][lane][c];
        if (start + c < SCAP) s_slab[w][start + c] = tt;
      }
    } else {
      // rare: per-element ballot-rank extraction from registers
      unsigned base = 0;
#pragma unroll
      for (int q = 0; q < 16; ++q) {
        const unsigned kk[4] = {kv[q].x, kv[q].y, kv[q].z, kv[q].w};
#pragma unroll
        for (int c = 0; c < 4; ++c) {
          const bool sel = kk[c] >= thrK;
          const unsigned long long mk = __ballot(sel);
          if (sel) {
            const unsigned pos = base + (unsigned)__popcll(mk & lt);
            if (pos < SCAP)
              s_slab[w][pos] =
                  make_uint2(kk[c], (unsigned)(q * 256 + lane * 4 + c));
          }
          base += (unsigned)__popcll(mk);
        }
      }
      total = base;
    }

    if (__builtin_expect(total > SCAP, 0)) {
      // parachute: exact 16th-largest of all 4096 (full-width register radix)
      unsigned p2 = 0, need2 = KSEL;
      for (int bit = 31; bit >= 0; --bit) {
        const unsigned want = (p2 << 1) | 1u;
        unsigned cnt = 0;
#pragma unroll
        for (int q = 0; q < 16; ++q) {
          cnt += (unsigned)__popcll(__ballot((kv[q].x >> bit) == want));
          cnt += (unsigned)__popcll(__ballot((kv[q].y >> bit) == want));
          cnt += (unsigned)__popcll(__ballot((kv[q].z >> bit) == want));
          cnt += (unsigned)__popcll(__ballot((kv[q].w >> bit) == want));
        }
        const bool take = cnt >= need2;
        p2 = want - (take ? 0u : 1u);
        need2 = take ? need2 : need2 - cnt;
      }
      s_slab[w][lane] = make_uint2(0u, 0xFFFFFFFFu);
      unsigned base = 0;
#pragma unroll
      for (int q = 0; q < 16; ++q) {
        const unsigned kk[4] = {kv[q].x, kv[q].y, kv[q].z, kv[q].w};
#pragma unroll
        for (int c = 0; c < 4; ++c) {
          const bool sel = kk[c] >= p2;
          const unsigned long long mk = __ballot(sel);
          if (sel) {
            const unsigned pos = base + (unsigned)__popcll(mk & lt);
            if (pos < SCAP)
              s_slab[w][pos] =
                  make_uint2(kk[c], (unsigned)(q * 256 + lane * 4 + c));
          }
          base += (unsigned)__popcll(mk);
        }
      }
    }

    // stage 2: exact tie-correct top-16 among <=64 padded candidates (1/lane)
    {
      const uint2 cc = s_slab[w][lane];  // same-wave RAW (lgkmcnt only)
      const unsigned cv = cc.x;
      const unsigned cj = cc.y;
      unsigned p2 = 0, need2 = KSEL;
      bool early = false;
      int bit = 31;
      for (; bit >= 0; --bit) {
        const unsigned want = (p2 << 1) | 1u;
        const unsigned cnt = (unsigned)__popcll(__ballot((cv >> bit) == want));
        if (cnt >= need2) {
          p2 = want;
          if (cnt == need2) { early = true; break; }
        } else {
          need2 -= cnt;
          p2 <<= 1;
        }
      }
      bool win;
      float vref;
      if (early) {
        const unsigned thr2 = p2 << bit;  // exactly KSEL candidates >= thr2
        win = cv >= thr2;
        vref = key2f(thr2);
      } else {
        win = cv > p2;
        vref = key2f(p2);
        bool tq = (cv == p2) && (cj != 0xFFFFFFFFu);
        for (unsigned q = 0; q < need2; ++q) {  // lowest-index ties (top_k)
          unsigned mi = tq ? cj : 0xFFFFFFFFu;
#pragma unroll
          for (int off = 32; off; off >>= 1) {
            const unsigned o = (unsigned)__shfl_xor((int)mi, off, 64);
            mi = o < mi ? o : mi;
          }
          if (tq && cj == mi) { win = true; tq = false; }
        }
      }
      const unsigned long long wm = __ballot(win);
      if (win) {
        const unsigned rk = (unsigned)__popcll(wm & lt);
        s_wj[w][rk] = make_uint2(__float_as_uint(__expf(key2f(cv) - vref)), cj);
      }
    }

    // gather (lane = 4 channels) + deferred softmax + per-row scalar stores
    float ssum = 0.f;
    float ax = 0.f, ay = 0.f, az = 0.f, aw2 = 0.f;
    if (FT) {
#pragma unroll
      for (int k = 0; k < KSEL; ++k) {
        const uint2 tt = s_wj[w][k];  // broadcast read
        const float ew = __uint_as_float(tt.x);
        ssum += ew;
        const float4 f = *(const float4*)(fb + (size_t)tt.y * N_CH);
        ax += ew * f.x; ay += ew * f.y; az += ew * f.z; aw2 += ew * f.w;
      }
    } else {
      const int c0s = lane * 4;
#pragma unroll
      for (int k = 0; k < KSEL; ++k) {
        const uint2 tt = s_wj[w][k];
        const float ew = __uint_as_float(tt.x);
        ssum += ew;
        ax += ew * fb[(size_t)(c0s + 0) * N_PIX + tt.y];
        ay += ew * fb[(size_t)(c0s + 1) * N_PIX + tt.y];
        az += ew * fb[(size_t)(c0s + 2) * N_PIX + tt.y];
        aw2 += ew * fb[(size_t)(c0s + 3) * N_PIX + tt.y];
      }
    }
    const float inv = 1.0f / ssum;
    const int i = row & (N_PIX - 1);
    float* op = out + ((size_t)(b * N_CH + lane * 4)) * N_PIX + i;
    op[0] = ax * inv;
    op[N_PIX] = ay * inv;
    op[2 * N_PIX] = az * inv;
    op[3 * N_PIX] = aw2 * inv;
  };

  // ---- depth-2 pipelined loads over the wave's 4 rows ----
  const float4* a0 = (const float4*)(aff + (size_t)(row0 + 0) * N_PIX);
  const float4* a1 = (const float4*)(aff + (size_t)(row0 + 1) * N_PIX);
  const float4* a2 = (const float4*)(aff + (size_t)(row0 + 2) * N_PIX);
  const float4* a3 = (const float4*)(aff + (size_t)(row0 + 3) * N_PIX);

  float4 fvA[16], fvB[16];
#pragma unroll
  for (int q = 0; q < 16; ++q) fvA[q] = a0[q * 64 + lane];  // row 0 -> A
#pragma unroll
  for (int q = 0; q < 16; ++q) fvB[q] = a1[q * 64 + lane];  // row 1 -> B
  process(fvA, row0 + 0);                                    // B in flight
#pragma unroll
  for (int q = 0; q < 16; ++q) fvA[q] = a2[q * 64 + lane];  // row 2 -> A
  process(fvB, row0 + 1);                                    // A in flight
#pragma unroll
  for (int q = 0; q < 16; ++q) fvB[q] = a3[q * 64 + lane];  // row 3 -> B
  process(fvA, row0 + 2);                                    // B in flight
  process(fvB, row0 + 3);
}

extern "C" void kernel_launch(void* const* d_in, const int* in_sizes, int n_in,
                              void* d_out, int out_size, void* d_ws, size_t ws_size,
                              hipStream_t stream) {
  const float* aff = (const float*)d_in[0];
  const float* feat = (const float*)d_in[1];
  float* out = (float*)d_out;
  const size_t feat_t_bytes = (size_t)2 * N_PIX * N_CH * sizeof(float);
  if (ws_size >= feat_t_bytes) {
    float* feat_t = (float*)d_ws;
    dim3 tb(32, 8, 1);
    dim3 tg(N_PIX / 32, N_CH / 32, 2);
    transpose_feat_kernel<<<tg, tb, 0, stream>>>(feat, feat_t);
    topk_pipe_kernel<true><<<512, 256, 0, stream>>>(aff, feat_t, out);
  } else {
    topk_pipe_kernel<false><<<512, 256, 0, stream>>>(aff, feat, out);
  }
}

// Round 12
// 51.990 us; speedup vs baseline: 1.1216x; 1.1216x over previous
//
#include <hip/hip_runtime.h>

#define N_PIX 4096
#define N_CH 256
#define KSEL 16
#define SCAP 64

__device__ __forceinline__ unsigned f2key(float f) {
  unsigned u = __float_as_uint(f);
  return u ^ ((unsigned)((int)u >> 31) | 0x80000000u);
}
__device__ __forceinline__ float key2f(unsigned k) {
  unsigned u = (k & 0x80000000u) ? (k ^ 0x80000000u) : ~k;
  return __uint_as_float(u);
}
__device__ __forceinline__ unsigned umax2(unsigned a, unsigned b) { return a > b ? a : b; }

// feat [B, C, N] -> feat_t [B, N, C], 32x32 LDS tile transpose
__global__ void transpose_feat_kernel(const float* __restrict__ feat,
                                      float* __restrict__ feat_t) {
  __shared__ float tile[32][33];
  const int b = blockIdx.z;
  const int n0 = blockIdx.x * 32;
  const int c0 = blockIdx.y * 32;
  const int tx = threadIdx.x, ty = threadIdx.y;
  const float* src = feat + (size_t)b * N_CH * N_PIX;
  float* dst = feat_t + (size_t)b * N_PIX * N_CH;
#pragma unroll
  for (int j = 0; j < 32; j += 8)
    tile[ty + j][tx] = src[(size_t)(c0 + ty + j) * N_PIX + n0 + tx];
  __syncthreads();
#pragma unroll
  for (int j = 0; j < 32; j += 8)
    dst[(size_t)(n0 + ty + j) * N_CH + c0 + tx] = tile[tx][ty + j];
}

// Block = 4 waves, ONE ROW PER WAVE, single pass, one barrier (output staging).
// Row resident as PACKED hi-16 keys: ph[32] (2 per reg) -> total VGPR ~100,
// under the 128 step => 4 waves/SIMD (2x R10's residency). Loads arrive in 4
// double-buffered batches of 4 x float4 (peak 32 transient regs).
//   T1  : exact 16th-largest hi-16-truncated lane max (16-step branchless
//         ballot radix). Candidates {hi16 >= T1} == {full key >= T1<<16}
//         (identical set; R9/R10-proven superset: >=16 elems, all top-16 in).
//   extr: per-lane candidate indices into 4 NAMED regs (static idx) + 3-ballot
//         prefix -> idx-only slab (pad ~0). No per-element ballots.
//   fetch: lane re-reads its slab candidate's float from L2 (row is hot).
//   st2 : exact tie-correct top-16 over <=64 padded candidates (1/lane,
//         early-exit ballot radix + lowest-index tie path; R10-proven).
// Parachutes: lane-overflow -> ballot-rank extraction from packed regs;
// slab-overflow -> streaming exact radix (R9). Both measure-zero, exact.
template <bool FT>
__global__ __launch_bounds__(256, 4) void topk_pk_kernel(
    const float* __restrict__ aff, const float* __restrict__ feat,
    float* __restrict__ out) {
  __shared__ unsigned s_slab[4][SCAP];  // candidate indices, ~0 = pad
  __shared__ uint2 s_wj[4][KSEL];       // (exp(v-vref) bits, idx)
  __shared__ float s_out[4][N_CH];

  const int tid = threadIdx.x;
  const int lane = tid & 63;
  const int w = tid >> 6;
  // chunked bijective XCD swizzle (2048 = 8*256): consecutive rg share an XCD
  // so the blocks writing each 64B output line write-combine in one L2.
  const int bid = blockIdx.x;
  const int rg = (bid & 7) * 256 + (bid >> 3);
  const int b = rg >> 10;
  const int i0 = (rg & 1023) * 4;
  const int row = rg * 4 + w;
  const unsigned long long lt = (1ull << lane) - 1ull;

  const float* arow_f = aff + (size_t)row * N_PIX;
  const float4* arow = (const float4*)arow_f;

  // ---- batched load (4 x 4 float4, double-buffered) + hi-16 pack ----
  unsigned ph[32];
  unsigned m = 0;
  float4 fvA[4], fvB[4];
#pragma unroll
  for (int r = 0; r < 4; ++r) fvA[r] = arow[r * 64 + lane];
#pragma unroll
  for (int bq = 0; bq < 4; ++bq) {
    if (bq < 3) {
#pragma unroll
      for (int r = 0; r < 4; ++r)
        fvB[r] = arow[((bq + 1) * 4 + r) * 64 + lane];
    }
#pragma unroll
    for (int r = 0; r < 4; ++r) {
      const int q = bq * 4 + r;
      const float4 v = fvA[r];
      const unsigned k0 = f2key(v.x), k1 = f2key(v.y);
      const unsigned k2 = f2key(v.z), k3 = f2key(v.w);
      m = umax2(m, umax2(umax2(k0, k1), umax2(k2, k3)));
      ph[2 * q + 0] = (k1 & 0xFFFF0000u) | (k0 >> 16);  // lo<-k0, hi<-k1
      ph[2 * q + 1] = (k3 & 0xFFFF0000u) | (k2 >> 16);  // lo<-k2, hi<-k3
    }
#pragma unroll
    for (int r = 0; r < 4; ++r) fvA[r] = fvB[r];
  }

  // ---- T1: exact 16th-largest truncated lane max (16-step branchless) ----
  const unsigned t = m >> 16;
  unsigned p1 = 0, need1 = KSEL;
#pragma unroll
  for (int bit = 15; bit >= 0; --bit) {
    const unsigned want = (p1 << 1) | 1u;
    const unsigned cnt = (unsigned)__popcll(__ballot((t >> bit) == want));
    const bool take = cnt >= need1;
    p1 = want - (take ? 0u : 1u);
    need1 = take ? need1 : need1 - cnt;
  }
  const unsigned T1 = p1;

  // pad slab (same-wave in-order DS ops; no barrier needed)
  s_slab[w][lane] = 0xFFFFFFFFu;

  // ---- extraction: candidates (hi16 >= T1) into 4 named regs ----
  unsigned cl = 0, j0 = 0, j1 = 0, j2 = 0, j3 = 0;
#pragma unroll
  for (int p = 0; p < 32; ++p) {
    const unsigned lo = ph[p] & 0xFFFFu;
    const unsigned hi = ph[p] >> 16;
    const unsigned jlo = (unsigned)((p >> 1) * 256 + lane * 4 + (p & 1) * 2);
    if (lo >= T1) {
      j3 = (cl == 3) ? jlo : j3; j2 = (cl == 2) ? jlo : j2;
      j1 = (cl == 1) ? jlo : j1; j0 = (cl == 0) ? jlo : j0;
      ++cl;
    }
    if (hi >= T1) {
      const unsigned jhi = jlo + 1;
      j3 = (cl == 3) ? jhi : j3; j2 = (cl == 2) ? jhi : j2;
      j1 = (cl == 1) ? jhi : j1; j0 = (cl == 0) ? jhi : j0;
      ++cl;
    }
  }

  unsigned total;
  if (__builtin_expect(__ballot(cl > 4) == 0ull, 1)) {
    // 3-ballot prefix sum of cl (0..4) -> compact positions
    const unsigned long long c0m = __ballot(cl & 1u);
    const unsigned long long c1m = __ballot(cl & 2u);
    const unsigned long long c2m = __ballot(cl & 4u);
    const unsigned start = (unsigned)__popcll(c0m & lt) +
                           2u * (unsigned)__popcll(c1m & lt) +
                           4u * (unsigned)__popcll(c2m & lt);
    total = (unsigned)__popcll(c0m) + 2u * (unsigned)__popcll(c1m) +
            4u * (unsigned)__popcll(c2m);
    if (cl > 0 && start + 0 < SCAP) s_slab[w][start + 0] = j0;
    if (cl > 1 && start + 1 < SCAP) s_slab[w][start + 1] = j1;
    if (cl > 2 && start + 2 < SCAP) s_slab[w][start + 2] = j2;
    if (cl > 3 && start + 3 < SCAP) s_slab[w][start + 3] = j3;
  } else {
    // rare lane-overflow: per-half ballot-rank extraction from packed regs
    unsigned base = 0;
#pragma unroll
    for (int p = 0; p < 32; ++p) {
      const unsigned lo = ph[p] & 0xFFFFu;
      const unsigned hi = ph[p] >> 16;
      const unsigned jlo = (unsigned)((p >> 1) * 256 + lane * 4 + (p & 1) * 2);
      {
        const bool sel = lo >= T1;
        const unsigned long long mk = __ballot(sel);
        if (sel) {
          const unsigned pos = base + (unsigned)__popcll(mk & lt);
          if (pos < SCAP) s_slab[w][pos] = jlo;
        }
        base += (unsigned)__popcll(mk);
      }
      {
        const bool sel = hi >= T1;
        const unsigned long long mk = __ballot(sel);
        if (sel) {
          const unsigned pos = base + (unsigned)__popcll(mk & lt);
          if (pos < SCAP) s_slab[w][pos] = jlo + 1;
        }
        base += (unsigned)__popcll(mk);
      }
    }
    total = base;
  }

  if (__builtin_expect(total <= SCAP, 1)) {
    // ---- fetch candidate floats (L2-hot) + stage 2 exact top-16 ----
    const unsigned jj = s_slab[w][lane];  // same-wave RAW (lgkmcnt only)
    const bool valid = jj != 0xFFFFFFFFu;
    const float fval = arow_f[valid ? jj : 0u];
    const unsigned cv = valid ? f2key(fval) : 0u;
    const unsigned cj = valid ? jj : 0xFFFFFFFFu;

    unsigned p2 = 0, need2 = KSEL;
    bool early = false;
    int bit = 31;
    for (; bit >= 0; --bit) {
      const unsigned want = (p2 << 1) | 1u;
      // pads (cv=0) never match an odd-prefixed want
      const unsigned cnt = (unsigned)__popcll(__ballot((cv >> bit) == want));
      if (cnt >= need2) {
        p2 = want;
        if (cnt == need2) { early = true; break; }
      } else {
        need2 -= cnt;
        p2 <<= 1;
      }
    }
    bool win;
    float vref;
    if (early) {
      const unsigned thr2 = p2 << bit;  // exactly KSEL candidates >= thr2
      win = cv >= thr2;
      vref = key2f(thr2);
    } else {
      win = cv > p2;
      vref = key2f(p2);
      bool tq = (cv == p2) && valid;
      for (unsigned q = 0; q < need2; ++q) {  // lowest-index ties (top_k)
        unsigned mi = tq ? cj : 0xFFFFFFFFu;
#pragma unroll
        for (int off = 32; off; off >>= 1) {
          const unsigned o = (unsigned)__shfl_xor((int)mi, off, 64);
          mi = o < mi ? o : mi;
        }
        if (tq && cj == mi) { win = true; tq = false; }
      }
    }
    const unsigned long long wm = __ballot(win);
    if (win) {
      const unsigned rk = (unsigned)__popcll(wm & lt);
      s_wj[w][rk] = make_uint2(__float_as_uint(__expf(key2f(cv) - vref)), cj);
    }
  } else {
    // ---- ultra-cold slab overflow: streaming exact radix over the row ----
    unsigned p2 = 0, need2 = KSEL;
    for (int bit = 31; bit >= 0; --bit) {
      const unsigned want = (p2 << 1) | 1u;
      unsigned cnt = 0;
      for (int q = 0; q < 16; ++q) {
        float4 v = arow[q * 64 + lane];
        cnt += (unsigned)__popcll(__ballot((f2key(v.x) >> bit) == want));
        cnt += (unsigned)__popcll(__ballot((f2key(v.y) >> bit) == want));
        cnt += (unsigned)__popcll(__ballot((f2key(v.z) >> bit) == want));
        cnt += (unsigned)__popcll(__ballot((f2key(v.w) >> bit) == want));
      }
      const bool take = cnt >= need2;
      p2 = want - (take ? 0u : 1u);
      need2 = take ? need2 : need2 - cnt;
    }
    const float vref = key2f(p2);
    unsigned rk = 0;
    for (int q = 0; q < 16; ++q) {
      float4 v = arow[q * 64 + lane];
      const float fvv[4] = {v.x, v.y, v.z, v.w};
      for (int c = 0; c < 4; ++c) {
        const unsigned kk = f2key(fvv[c]);
        const bool sel = kk > p2;
        const unsigned long long mk = __ballot(sel);
        if (sel) {
          const unsigned pos = rk + (unsigned)__popcll(mk & lt);
          if (pos < KSEL)
            s_wj[w][pos] = make_uint2(__float_as_uint(__expf(fvv[c] - vref)),
                                      (unsigned)(q * 256 + lane * 4 + c));
        }
        rk += (unsigned)__popcll(mk);
      }
    }
    unsigned jprev = 0xFFFFFFFFu;
    for (unsigned tq = rk; tq < KSEL; ++tq) {  // lowest-index ties, ascending
      unsigned mi = 0xFFFFFFFFu;
      for (int q = 0; q < 16; ++q) {
        float4 v = arow[q * 64 + lane];
        const float fvv[4] = {v.x, v.y, v.z, v.w};
        for (int c = 0; c < 4; ++c) {
          const unsigned j = (unsigned)(q * 256 + lane * 4 + c);
          if (f2key(fvv[c]) == p2 && (jprev == 0xFFFFFFFFu || j > jprev) && j < mi)
            mi = j;
        }
      }
#pragma unroll
      for (int off = 32; off; off >>= 1) {
        const unsigned o = (unsigned)__shfl_xor((int)mi, off, 64);
        mi = o < mi ? o : mi;
      }
      if (lane == 0) s_wj[w][tq] = make_uint2(__float_as_uint(1.0f), mi);
      jprev = mi;
    }
  }

  // ---- epilogue (same-wave LDS RAW): softmax denom + gather, lane = 4 ch ----
  float ssum = 0.f;
#pragma unroll
  for (int k = 0; k < KSEL; ++k) ssum += __uint_as_float(s_wj[w][k].x);
  const float inv = 1.0f / ssum;

  float ax = 0.f, ay = 0.f, az = 0.f, aw2 = 0.f;
  if (FT) {
    const float* fb = feat + (size_t)b * N_PIX * N_CH + lane * 4;  // [B,N,C]
#pragma unroll
    for (int k = 0; k < KSEL; ++k) {
      const uint2 tt = s_wj[w][k];  // broadcast read
      const float ew = __uint_as_float(tt.x);
      const float4 f = *(const float4*)(fb + (size_t)tt.y * N_CH);
      ax += ew * f.x; ay += ew * f.y; az += ew * f.z; aw2 += ew * f.w;
    }
  } else {
    const float* fb = feat + (size_t)b * N_CH * N_PIX;  // [B,C,N] fallback
    const int c0s = lane * 4;
#pragma unroll
    for (int k = 0; k < KSEL; ++k) {
      const uint2 tt = s_wj[w][k];
      const float ew = __uint_as_float(tt.x);
      ax += ew * fb[(size_t)(c0s + 0) * N_PIX + tt.y];
      ay += ew * fb[(size_t)(c0s + 1) * N_PIX + tt.y];
      az += ew * fb[(size_t)(c0s + 2) * N_PIX + tt.y];
      aw2 += ew * fb[(size_t)(c0s + 3) * N_PIX + tt.y];
    }
  }
  float4 accv;
  accv.x = ax * inv; accv.y = ay * inv; accv.z = az * inv; accv.w = aw2 * inv;
  *(float4*)&s_out[w][lane * 4] = accv;

  __syncthreads();  // the only block barrier: full-line output assembly

  {
    const int c = tid;
    float4 o;
    o.x = s_out[0][c]; o.y = s_out[1][c]; o.z = s_out[2][c]; o.w = s_out[3][c];
    *(float4*)(out + ((size_t)(b * N_CH + c)) * N_PIX + i0) = o;
  }
}

extern "C" void kernel_launch(void* const* d_in, const int* in_sizes, int n_in,
                              void* d_out, int out_size, void* d_ws, size_t ws_size,
                              hipStream_t stream) {
  const float* aff = (const float*)d_in[0];
  const float* feat = (const float*)d_in[1];
  float* out = (float*)d_out;
  const size_t feat_t_bytes = (size_t)2 * N_PIX * N_CH * sizeof(float);
  if (ws_size >= feat_t_bytes) {
    float* feat_t = (float*)d_ws;
    dim3 tb(32, 8, 1);
    dim3 tg(N_PIX / 32, N_CH / 32, 2);
    transpose_feat_kernel<<<tg, tb, 0, stream>>>(feat, feat_t);
    topk_pk_kernel<true><<<2048, 256, 0, stream>>>(aff, feat_t, out);
  } else {
    topk_pk_kernel<false><<<2048, 256, 0, stream>>>(aff, feat, out);
  }
}